// Round 8
// baseline (200.579 us; speedup 1.0000x reference)
//
#include <hip/hip_runtime.h>

#define RES 512
#define PS 64
#define NPATCH 512
#define BATCH 16
#define NTILE 8                              // 8x8 tiles of 64x64 per image

// Single fused kernel. One block per (b, 64x64 tile, 16-row band): 4096 blocks.
// Stage: block scans its batch's 512 coords (64KB, L2/L3-broadcast) and keeps
// patches overlapping its 16x64 region in LDS, padded to a multiple of 16 with
// column-invalid dummies so the hot loop has no remainder.
// Gather: thread owns 4 rows x 1 col. Row math is wave-uniform -> forced to
// SALU via readfirstlane; loads are scalar-base + shared voffset. Branch-free
// clamped loads + masked FMA accumulate.
__global__ __launch_bounds__(256, 4) void fused_gather_kernel(
        const float* __restrict__ logits,
        const int*   __restrict__ coords,
        float* __restrict__ out) {
    __shared__ unsigned sl[NPATCH + 16];
    __shared__ int s_m;

    int blk  = blockIdx.x;
    int band = blk & 3;                      // 16-row band within tile
    int list = blk >> 2;                     // b*64 + tr*8 + tc
    int b  = list >> 6;
    int tr = (list >> 3) & 7;
    int tc = list & 7;
    int R0 = tr * 64 + band * 16;            // first global row of this block
    int C0 = tc * 64;                        // first global col of this block

    if (threadIdx.x == 0) s_m = 0;
    __syncthreads();

    // ---- stage: filter this batch's patches to my 16x64 region ----
    const int2* cb = (const int2*)(coords + (size_t)b * NPATCH * 2);
    for (int k = threadIdx.x; k < NPATCH; k += 256) {
        int2 c = cb[k];                      // (ch, cw), each in [0,448]
        int ch = c.x, cw = c.y;
        if (ch <= R0 + 15 && ch >= R0 - 63 && cw <= C0 + 63 && cw >= C0 - 63) {
            unsigned pack = (unsigned)k | ((unsigned)ch << 10) | ((unsigned)cw << 19);
            sl[atomicAdd(&s_m, 1)] = pack;
        }
    }
    __syncthreads();
    int m  = s_m;
    int mp = (m + 15) & ~15;                 // pad to multiple of 16
    // dummy: cw=(C0+256)&511 makes (gcol-cw) >= 64 for EVERY lane of this
    // block -> colw = 0 -> contributes nothing; k=0,ch=0 loads are harmless
    // in-bounds reads of patch 0.
    if (threadIdx.x < (unsigned)(mp - m))
        sl[m + threadIdx.x] = ((unsigned)((C0 + 256) & 511)) << 19;
    __syncthreads();

    // ---- gather ----
    int lane  = threadIdx.x & 63;            // column within tile
    int w     = threadIdx.x >> 6;            // wave id: 4-row group
    int gcol4 = (C0 + lane) << 2;            // global column, byte-scaled (VGPR)
    // row0 is wave-uniform: force it scalar so all row math goes SALU.
    int row0  = __builtin_amdgcn_readfirstlane(R0 + w * 4);

    float sum0 = 0.f, sum1 = 0.f, sum2 = 0.f, sum3 = 0.f;
    float cc0  = 0.f, cc1  = 0.f, cc2  = 0.f, cc3  = 0.f;

#pragma unroll 16
    for (int i = 0; i < mp; ++i) {
        unsigned e = __builtin_amdgcn_readfirstlane(sl[i]);  // scalar decode
        int k   = e & 1023;
        int ch  = (e >> 10) & 511;
        int cw4 = ((e >> 19) & 511) << 2;

        int t = gcol4 - cw4;                             // per-lane byte col
        float colw = ((unsigned)t < 256u) ? 1.0f : 0.0f;
        int voff = min(max(t, 0), 252);                  // v_med3: shared voffset

        int dr0 = row0 - ch;                             // SCALAR row in patch
        const char* p = (const char*)(logits + ((size_t)((b << 9) + k) << 12));

        // scalar clamped row byte-offsets -> 4 scalar bases, shared voff
        const char* p0 = p + (min(max(dr0 + 0, 0), 63) << 8);
        const char* p1 = p + (min(max(dr0 + 1, 0), 63) << 8);
        const char* p2 = p + (min(max(dr0 + 2, 0), 63) << 8);
        const char* p3 = p + (min(max(dr0 + 3, 0), 63) << 8);
        float v0 = *(const float*)(p0 + voff);           // always load; L1/L2
        float v1 = *(const float*)(p1 + voff);           //   eat the clamp dups
        float v2 = *(const float*)(p2 + voff);
        float v3 = *(const float*)(p3 + voff);
        float w0 = ((unsigned)(dr0 + 0) < 64u) ? colw : 0.0f;  // scc-select
        float w1 = ((unsigned)(dr0 + 1) < 64u) ? colw : 0.0f;
        float w2 = ((unsigned)(dr0 + 2) < 64u) ? colw : 0.0f;
        float w3 = ((unsigned)(dr0 + 3) < 64u) ? colw : 0.0f;
        sum0 += v0 * w0;  cc0 += w0;
        sum1 += v1 * w1;  cc1 += w1;
        sum2 += v2 * w2;  cc2 += w2;
        sum3 += v3 * w3;  cc3 += w3;
    }

    size_t obase = ((size_t)b * RES + row0) * RES + (gcol4 >> 2);
    __builtin_nontemporal_store(sum0 / fmaxf(cc0, 1.0f), &out[obase + 0 * RES]);
    __builtin_nontemporal_store(sum1 / fmaxf(cc1, 1.0f), &out[obase + 1 * RES]);
    __builtin_nontemporal_store(sum2 / fmaxf(cc2, 1.0f), &out[obase + 2 * RES]);
    __builtin_nontemporal_store(sum3 / fmaxf(cc3, 1.0f), &out[obase + 3 * RES]);
}

extern "C" void kernel_launch(void* const* d_in, const int* in_sizes, int n_in,
                              void* d_out, int out_size, void* d_ws, size_t ws_size,
                              hipStream_t stream) {
    const float* logits = (const float*)d_in[0];  // [16,512,1,64,64] f32
    const int*   coords = (const int*)d_in[1];    // [16,512,2] i32
    float* out = (float*)d_out;                   // [16,1,512,512] f32
    (void)d_ws; (void)ws_size;

    fused_gather_kernel<<<BATCH * NTILE * NTILE * 4, 256, 0, stream>>>(logits, coords, out);
}